// Round 6
// baseline (301.110 us; speedup 1.0000x reference)
//
#include <hip/hip_runtime.h>
#include <hip/hip_bf16.h>

// Problem sizes
#define NB 4
#define DIMC 64
#define C2 256
#define HFC 128
#define HH 256
#define WW 256
#define HW (HH * WW)

typedef __attribute__((ext_vector_type(8))) short short8;
typedef __attribute__((ext_vector_type(4))) short s16x4;
typedef __attribute__((ext_vector_type(4))) float f32x4;

__device__ __forceinline__ f32x4 mfma16(short8 a, short8 b, f32x4 c) {
  return __builtin_amdgcn_mfma_f32_16x16x32_bf16(a, b, c, 0, 0, 0);
}

__device__ __forceinline__ short f2bs(float f) {
  __hip_bfloat16 h = __float2bfloat16(f);
  union { __hip_bfloat16 h; short s; } u; u.h = h;
  return u.s;
}

__device__ __forceinline__ float bs2f(short s) {
  union { float f; unsigned u; } v;
  v.u = ((unsigned)(unsigned short)s) << 16;
  return v.f;
}

// ---------------------------------------------------------------------------
// prep: build (a) per-channel 64x64 spectral matrices from fft_filt, as MFMA
// A-fragments; (b) w_in / w_out bf16 fragments.
// Fragment-major layout: [mblk][kblk][lane(64)][j(8)]; lane's 8 bf16 are
// X[m=lane&15][k=kblk*32+(lane>>4)*8+j] (A and B lane layouts are identical
// for 16x16x32, so these serve as either operand).
// ---------------------------------------------------------------------------
__global__ __launch_bounds__(64) void prep_kernel(
    const float* __restrict__ w_in, const float* __restrict__ fft,
    const float* __restrict__ w_out, __hip_bfloat16* __restrict__ A1,
    __hip_bfloat16* __restrict__ A2, __hip_bfloat16* __restrict__ Mf) {
  int blk = blockIdx.x;
  int l = threadIdx.x;
  int mm = l & 15, qj = l >> 4;
  if (blk < C2) {
    __shared__ float Feff[64];
    __shared__ float kc[64];
    __shared__ float ct[8];
    if (l < 8) {
      const float s = 0.70710678118654752f;
      const float v0[8] = {1.f, s, 0.f, -s, -1.f, -s, 0.f, s};
      ct[l] = v0[l];
    }
    int c = blk;
    const float* f = fft + c * 40;  // [u][v], v in [0,5)
    int u = l >> 3, v = l & 7;
    int um = (8 - u) & 7;
    float val;
    if (v <= 4) {
      val = f[u * 5 + v];
      // pocketfft c2r ignores imag of DC/Nyquist bins -> u-symmetrize
      if (v == 0 || v == 4) val = 0.5f * (val + f[um * 5 + v]);
    } else {
      val = f[um * 5 + (8 - v)];  // Hermitian extension (filter is real)
    }
    Feff[l] = val;
    __syncthreads();
    int dy = l >> 3, dx = l & 7;
    float s = 0.f;
    for (int uu = 0; uu < 8; ++uu)
      for (int vv = 0; vv < 8; ++vv)
        s += Feff[uu * 8 + vv] * ct[(uu * dy + vv * dx) & 7];
    kc[l] = s * (1.f / 64.f);
    __syncthreads();
    for (int mb = 0; mb < 4; ++mb) {
      int p = mb * 16 + mm;
      int py = p >> 3, px = p & 7;
      for (int kb = 0; kb < 2; ++kb)
        for (int j = 0; j < 8; ++j) {
          int q = kb * 32 + qj * 8 + j;
          int qy = q >> 3, qx = q & 7;
          float kv = kc[((py - qy) & 7) * 8 + ((px - qx) & 7)];
          Mf[(size_t)c * 4096 + (size_t)((mb * 2 + kb) * 64 + l) * 8 + j] =
              __float2bfloat16(kv);
        }
    }
  } else if (blk == C2) {
    // w_in (256x64) fragments: 16 mblk x 2 kblk
    for (int mb = 0; mb < 16; ++mb)
      for (int kb = 0; kb < 2; ++kb)
        for (int j = 0; j < 8; ++j) {
          int m = mb * 16 + mm, k = kb * 32 + qj * 8 + j;
          A1[(size_t)((mb * 2 + kb) * 64 + l) * 8 + j] =
              __float2bfloat16(w_in[m * 64 + k]);
        }
  } else {
    // w_out (64x128) fragments: 4 mblk x 4 kblk
    for (int mb = 0; mb < 4; ++mb)
      for (int kb = 0; kb < 4; ++kb)
        for (int j = 0; j < 8; ++j) {
          int m = mb * 16 + mm, k = kb * 32 + qj * 8 + j;
          A2[(size_t)((mb * 4 + kb) * 64 + l) * 8 + j] =
              __float2bfloat16(w_out[m * 128 + k]);
        }
  }
}

// ---------------------------------------------------------------------------
// gemm1 (all batches): h[b][c][pix] = sum_d w_in[c][d] * x[b][d][pix], bf16.
// Computed TRANSPOSED: D[m=pix][n=c] = x^T @ w_in^T, so each lane's 4 acc
// regs are 4 consecutive pixels -> b64 stores (16 per thread, no LDS repack).
// ---------------------------------------------------------------------------
__global__ __launch_bounds__(256) void gemm1_kernel(
    const float* __restrict__ x, const __hip_bfloat16* __restrict__ A1,
    __hip_bfloat16* __restrict__ h1) {
  __shared__ short Bt[8 * 64 * 8];  // x frags: [kblk*4+pxtile][lane][j] 8 KiB
  int b = blockIdx.y;
  int n0 = blockIdx.x * 64;
  int t = threadIdx.x;
  int n = t & 63, dgrp = t >> 6;
  int nblk = n >> 4, nn = n & 15;
  const float* xb = x + (size_t)b * DIMC * HW + n0 + n;
#pragma unroll
  for (int s = 0; s < 2; ++s) {
    int jb = dgrp + s * 4;  // [0,8): d-block of 8
    int kb = jb >> 2, quad = jb & 3;
    short8 pk;
#pragma unroll
    for (int j = 0; j < 8; ++j) pk[j] = f2bs(xb[(size_t)(jb * 8 + j) * HW]);
    *reinterpret_cast<short8*>(&Bt[((kb * 4 + nblk) * 64 + quad * 16 + nn) * 8]) = pk;
  }
  __syncthreads();
  int w = t >> 6, l = t & 63;
  int quad = l >> 4, ln = l & 15;
  const short8* A1v = reinterpret_cast<const short8*>(A1);
  short8 wf[4][2];  // w_in fragments as B-operand: c-tile = w*64 + ot*16
#pragma unroll
  for (int ot = 0; ot < 4; ++ot)
#pragma unroll
    for (int kb = 0; kb < 2; ++kb)
      wf[ot][kb] = A1v[((w * 4 + ot) * 2 + kb) * 64 + l];
  const short8* Bv = reinterpret_cast<const short8*>(Bt);
  f32x4 acc[4][4];  // [mt=pix][ot=c]
#pragma unroll
  for (int i = 0; i < 4; ++i)
#pragma unroll
    for (int j = 0; j < 4; ++j) acc[i][j] = (f32x4){0.f, 0.f, 0.f, 0.f};
#pragma unroll
  for (int mt = 0; mt < 4; ++mt) {
    short8 a0 = Bv[(0 * 4 + mt) * 64 + l];
    short8 a1 = Bv[(1 * 4 + mt) * 64 + l];
#pragma unroll
    for (int ot = 0; ot < 4; ++ot) {
      acc[mt][ot] = mfma16(a0, wf[ot][0], acc[mt][ot]);
      acc[mt][ot] = mfma16(a1, wf[ot][1], acc[mt][ot]);
    }
  }
#pragma unroll
  for (int mt = 0; mt < 4; ++mt)
#pragma unroll
    for (int ot = 0; ot < 4; ++ot) {
      int c = w * 64 + ot * 16 + ln;
      int px = n0 + mt * 16 + quad * 4;
      s16x4 v;
#pragma unroll
      for (int r = 0; r < 4; ++r) v[r] = f2bs(acc[mt][ot][r]);
      *reinterpret_cast<s16x4*>(&h1[((size_t)b * C2 + c) * HW + px]) = v;
    }
}

// ---------------------------------------------------------------------------
// spectral (all batches, IN-PLACE): per channel c, patch: h <- M_c @ h.
// D[m=p][n=patch]; p = quad*4+r means the 4 acc regs are 4 consecutive x
// within one patch row -> b64 stores. Blocks touch disjoint h regions.
// ---------------------------------------------------------------------------
__global__ __launch_bounds__(256) void spectral_kernel(
    __hip_bfloat16* hb, const __hip_bfloat16* __restrict__ Mf) {
  int c = blockIdx.y;
  int t0 = blockIdx.x * 256;
  int tid = threadIdx.x;
  int w = tid >> 6, l = tid & 63;
  int quad = l >> 4, ln = l & 15;
  const short8* Mv = reinterpret_cast<const short8*>(Mf + (size_t)c * 4096);
  short8 af[4][2];
#pragma unroll
  for (int mb = 0; mb < 4; ++mb)
#pragma unroll
    for (int kb = 0; kb < 2; ++kb) af[mb][kb] = Mv[(mb * 2 + kb) * 64 + l];
  f32x4 acc[4][4];
#pragma unroll
  for (int i = 0; i < 4; ++i)
#pragma unroll
    for (int j = 0; j < 4; ++j) acc[i][j] = (f32x4){0.f, 0.f, 0.f, 0.f};
#pragma unroll
  for (int nb = 0; nb < 4; ++nb) {
    int tp = t0 + w * 64 + nb * 16 + ln;  // patch id: b*1024 + Py*32 + Px
    int bb = tp >> 10, Py = (tp >> 5) & 31, Px = tp & 31;
    const __hip_bfloat16* base =
        hb + (((size_t)bb * C2 + c) * HH + Py * 8) * WW + Px * 8;
    short8 bf0 = *reinterpret_cast<const short8*>(base + (size_t)quad * WW);
    short8 bf1 = *reinterpret_cast<const short8*>(base + (size_t)(4 + quad) * WW);
#pragma unroll
    for (int mb = 0; mb < 4; ++mb) {
      acc[mb][nb] = mfma16(af[mb][0], bf0, acc[mb][nb]);
      acc[mb][nb] = mfma16(af[mb][1], bf1, acc[mb][nb]);
    }
  }
  __syncthreads();  // all reads of this block's patches complete before writes
#pragma unroll
  for (int nb = 0; nb < 4; ++nb) {
    int tp = t0 + w * 64 + nb * 16 + ln;
    int bb = tp >> 10, Py = (tp >> 5) & 31, Px = tp & 31;
#pragma unroll
    for (int mb = 0; mb < 4; ++mb) {
      int y = Py * 8 + 2 * mb + (quad >> 1);
      int xx = Px * 8 + (quad & 1) * 4;
      s16x4 v;
#pragma unroll
      for (int r = 0; r < 4; ++r) v[r] = f2bs(acc[mb][nb][r]);
      *reinterpret_cast<s16x4*>(
          &hb[(((size_t)bb * C2 + c) * HH + y) * WW + xx]) = v;
    }
  }
}

// ---------------------------------------------------------------------------
// dwgelu (all batches): depthwise 3x3 (SAME) + gelu-gate, coalesced loads,
// LDS transpose repack into gemm2 fragment layout (b128 global stores).
// ---------------------------------------------------------------------------
__global__ __launch_bounds__(256) void dwgelu_kernel(
    const __hip_bfloat16* __restrict__ h2, const float* __restrict__ w_dw,
    __hip_bfloat16* __restrict__ gf) {
  __shared__ short ldsJ[8 * 1024];  // [j][B = r*256 + px], 16 KiB
  int jb = blockIdx.x;     // [0,16)
  int y0 = blockIdx.y * 4; // strip rows y0..y0+3
  int b = blockIdx.z;
  int t = threadIdx.x;
  int j = t >> 5, xg = t & 31;
  int x0 = xg * 8;
  int c1 = jb * 8 + j, c2 = c1 + HFC;
  const __hip_bfloat16* hbase = h2 + (size_t)b * C2 * HW;

  float wd1[9], wd2[9];
#pragma unroll
  for (int k = 0; k < 9; ++k) {
    wd1[k] = w_dw[c1 * 9 + k];
    wd2[k] = w_dw[c2 * 9 + k];
  }

  float acc1[4][8], acc2[4][8];
#pragma unroll
  for (int r = 0; r < 4; ++r)
#pragma unroll
    for (int i = 0; i < 8; ++i) { acc1[r][i] = 0.f; acc2[r][i] = 0.f; }

#pragma unroll
  for (int ir = -1; ir <= 4; ++ir) {
    int yy = y0 + ir;
    bool valid = (yy >= 0) && (yy < HH);
    float f1[10], f2[10];
    if (valid) {
      const __hip_bfloat16* r1 = hbase + ((size_t)c1 * HH + yy) * WW;
      const __hip_bfloat16* r2 = hbase + ((size_t)c2 * HH + yy) * WW;
      short8 v1 = *reinterpret_cast<const short8*>(r1 + x0);
      short8 v2 = *reinterpret_cast<const short8*>(r2 + x0);
#pragma unroll
      for (int i = 0; i < 8; ++i) { f1[i + 1] = bs2f(v1[i]); f2[i + 1] = bs2f(v2[i]); }
      f1[0] = (x0 > 0) ? __bfloat162float(r1[x0 - 1]) : 0.f;
      f2[0] = (x0 > 0) ? __bfloat162float(r2[x0 - 1]) : 0.f;
      f1[9] = (x0 + 8 < WW) ? __bfloat162float(r1[x0 + 8]) : 0.f;
      f2[9] = (x0 + 8 < WW) ? __bfloat162float(r2[x0 + 8]) : 0.f;
    } else {
#pragma unroll
      for (int i = 0; i < 10; ++i) { f1[i] = 0.f; f2[i] = 0.f; }
    }
#pragma unroll
    for (int dy = -1; dy <= 1; ++dy) {
      int r = ir - dy;
      if (r < 0 || r >= 4) continue;
      int ky = dy + 1;
#pragma unroll
      for (int i = 0; i < 8; ++i) {
        acc1[r][i] += f1[i] * wd1[ky * 3] + f1[i + 1] * wd1[ky * 3 + 1] +
                      f1[i + 2] * wd1[ky * 3 + 2];
        acc2[r][i] += f2[i] * wd2[ky * 3] + f2[i + 1] * wd2[ky * 3 + 1] +
                      f2[i + 2] * wd2[ky * 3 + 2];
      }
    }
  }

  // gate + one b128 LDS write per row (lanes contiguous: conflict-free)
#pragma unroll
  for (int r = 0; r < 4; ++r) {
    short8 pk;
#pragma unroll
    for (int i = 0; i < 8; ++i) {
      float u = acc1[r][i];
      float g = 0.5f * u * (1.f + erff(u * 0.70710678118654752f));
      pk[i] = f2bs(g * acc2[r][i]);
    }
    *reinterpret_cast<short8*>(&ldsJ[j * 1024 + r * 256 + x0]) = pk;
  }
  __syncthreads();

  // gather fragments: 8 u16 reads (2 lanes/word = free) + b128 store
  int kb = jb >> 2, quad = jb & 3;
  short8* gfv = reinterpret_cast<short8*>(gf) + (size_t)b * 1048576;
#pragma unroll
  for (int k = 0; k < 4; ++k) {
    short8 v;
#pragma unroll
    for (int j2 = 0; j2 < 8; ++j2) v[j2] = ldsJ[j2 * 1024 + k * 256 + t];
    int pix = (y0 + k) * WW + t;
    gfv[((size_t)(pix >> 4) * 4 + kb) * 64 + quad * 16 + (pix & 15)] = v;
  }
}

// ---------------------------------------------------------------------------
// gemm2 (all batches): out[b][o][pix] = sum_hf w_out[o][hf]*g[b][hf][pix].
// Computed TRANSPOSED: D[m=pix][n=o], so each acc reg quad is 4 consecutive
// pixels -> direct dwordx4 stores (acc IS the float4). No LDS.
// ---------------------------------------------------------------------------
__global__ __launch_bounds__(256) void gemm2_kernel(
    const __hip_bfloat16* __restrict__ gf, const __hip_bfloat16* __restrict__ A2,
    float* __restrict__ out) {
  int b = blockIdx.y;
  int pix0 = blockIdx.x * 256;
  int tid = threadIdx.x;
  int w = tid >> 6, l = tid & 63;
  int quad = l >> 4, ln = l & 15;
  const short8* A2v = reinterpret_cast<const short8*>(A2);
  short8 wf[4][4];  // w_out fragments as B-operand: o-tile ot
#pragma unroll
  for (int ot = 0; ot < 4; ++ot)
#pragma unroll
    for (int kb = 0; kb < 4; ++kb) wf[ot][kb] = A2v[(ot * 4 + kb) * 64 + l];
  const short8* gv = reinterpret_cast<const short8*>(gf) + (size_t)b * 1048576;
  f32x4 acc[4][4];  // [mt=pix][ot=o]
#pragma unroll
  for (int i = 0; i < 4; ++i)
#pragma unroll
    for (int j = 0; j < 4; ++j) acc[i][j] = (f32x4){0.f, 0.f, 0.f, 0.f};
#pragma unroll
  for (int mt = 0; mt < 4; ++mt) {
    size_t pixblk = (size_t)blockIdx.x * 16 + w * 4 + mt;
    short8 af[4];
#pragma unroll
    for (int kb = 0; kb < 4; ++kb) af[kb] = gv[(pixblk * 4 + kb) * 64 + l];
#pragma unroll
    for (int ot = 0; ot < 4; ++ot)
#pragma unroll
      for (int kb = 0; kb < 4; ++kb)
        acc[mt][ot] = mfma16(af[kb], wf[ot][kb], acc[mt][ot]);
  }
#pragma unroll
  for (int mt = 0; mt < 4; ++mt)
#pragma unroll
    for (int ot = 0; ot < 4; ++ot) {
      int o = ot * 16 + ln;
      int px = pix0 + w * 64 + mt * 16 + quad * 4;
      *reinterpret_cast<f32x4*>(&out[((size_t)b * DIMC + o) * HW + px]) =
          acc[mt][ot];
    }
}

// ---------------------------------------------------------------------------
// Workspace layout (bytes). ws_size = 256 MiB:
//   0          A1 (w_in frags)     32768
//   32768      A2 (w_out frags)    16384
//   49152      Mf (spectral mats)  2097152
//   2146304    gf (g frags, 4 b)   67108864
//   69255168   h  (bf16, 4 b)      134217728
// total 203,472,896 B (~194 MiB) <= 256 MiB. All offsets 16B-aligned.
// ---------------------------------------------------------------------------
extern "C" void kernel_launch(void* const* d_in, const int* in_sizes, int n_in,
                              void* d_out, int out_size, void* d_ws,
                              size_t ws_size, hipStream_t stream) {
  const float* x = (const float*)d_in[0];
  const float* w_in = (const float*)d_in[1];
  const float* w_dw = (const float*)d_in[2];
  const float* fft = (const float*)d_in[3];
  const float* w_out = (const float*)d_in[4];
  float* out = (float*)d_out;
  char* ws = (char*)d_ws;
  __hip_bfloat16* A1 = (__hip_bfloat16*)(ws);
  __hip_bfloat16* A2 = (__hip_bfloat16*)(ws + 32768);
  __hip_bfloat16* Mf = (__hip_bfloat16*)(ws + 49152);
  __hip_bfloat16* gf = (__hip_bfloat16*)(ws + 2146304);
  __hip_bfloat16* h = (__hip_bfloat16*)(ws + 69255168);

  prep_kernel<<<258, 64, 0, stream>>>(w_in, fft, w_out, A1, A2, Mf);
  gemm1_kernel<<<dim3(1024, NB), 256, 0, stream>>>(x, A1, h);
  spectral_kernel<<<dim3(16, C2), 256, 0, stream>>>(h, Mf);
  dwgelu_kernel<<<dim3(16, 64, NB), 256, 0, stream>>>(h, w_dw, gf);
  gemm2_kernel<<<dim3(256, NB), 256, 0, stream>>>(gf, A2, out);
}